// Round 6
// baseline (247.952 us; speedup 1.0000x reference)
//
#include <hip/hip_runtime.h>
#include <hip/hip_bf16.h>
#include <stdint.h>
#include <math.h>

#define KDIM 2304   // 9 * 256

typedef __attribute__((ext_vector_type(8))) short bf16x8;
typedef __attribute__((ext_vector_type(8))) unsigned short u16x8;
typedef __attribute__((ext_vector_type(4))) float f32x4;

__device__ inline unsigned short f2bf(float f) {
  union { float f; unsigned int u; } v; v.f = f;
  unsigned int u = v.u;
  unsigned int r = (u + 0x7FFFu + ((u >> 16) & 1u)) >> 16;
  return (unsigned short)r;
}
__device__ inline float bf2f(unsigned short h) {
  union { unsigned int u; float f; } v; v.u = ((unsigned int)h) << 16;
  return v.f;
}

// ---------------------------------------------------------------------------
// Kernel 1: x (B,C,H,W) fp32 -> xTb (B,H,W,C) bf16
// ---------------------------------------------------------------------------
__global__ __launch_bounds__(256) void k_transpose(const float* __restrict__ x,
                                                   unsigned short* __restrict__ xTb) {
  __shared__ float tile[32][33];
  int t = threadIdx.x;
  int tx = t & 31, ty = t >> 5;
  int p0 = blockIdx.x * 32;
  int c0 = blockIdx.y * 32;
  int b  = blockIdx.z;
  const float* xb = x + ((size_t)b << 20);
#pragma unroll
  for (int i = 0; i < 4; ++i) {
    int c = c0 + ty + i * 8;
    tile[ty + i * 8][tx] = xb[((size_t)c << 12) + p0 + tx];
  }
  __syncthreads();
  unsigned short* ob = xTb + ((size_t)b << 20);
#pragma unroll
  for (int i = 0; i < 4; ++i) {
    int p = p0 + ty + i * 8;
    ob[(((size_t)p) << 8) + c0 + tx] = f2bf(tile[tx][ty + i * 8]);
  }
}

// ---------------------------------------------------------------------------
// Kernel 2: weight prep (Wpk in A-fragment order; Wob row-major; zero page).
// ---------------------------------------------------------------------------
__global__ __launch_bounds__(256) void k_wprep(const float* __restrict__ dcn_w,
                                               const float* __restrict__ offset_w,
                                               unsigned short* __restrict__ Wpk,
                                               unsigned short* __restrict__ Wob,
                                               unsigned short* __restrict__ zp) {
  int gid = blockIdx.x * 256 + threadIdx.x;
  const int N1 = 72 * 8192;
  const int N2 = 32 * KDIM;
  if (gid < N1) {
    int j = gid & 7;
    int lane = (gid >> 3) & 63;
    int mb = (gid >> 9) & 15;
    int kc = gid >> 13;
    int row = mb * 16 + (lane & 15);
    int gk = kc * 32 + ((lane >> 4) << 3) + j;
    int c = gk & 255, kidx = gk >> 8;
    Wpk[gid] = f2bf(dcn_w[((size_t)(row * 256 + c)) * 9 + kidx]);
  } else if (gid < N1 + N2) {
    int g = gid - N1;
    int ch = g / KDIM, k = g % KDIM;
    int kidx = k >> 8, c = k & 255;
    Wob[g] = (ch < 27) ? f2bf(offset_w[((size_t)(ch * 256 + c)) * 9 + kidx])
                       : (unsigned short)0;
  } else if (gid < N1 + N2 + 256) {
    zp[gid - N1 - N2] = 0;
  }
}

// ---------------------------------------------------------------------------
// Kernel 3: offset conv GEMM — NO LDS, NO BARRIERS.
//  Wave = 16 bhw rows x 32 ch. A- and B-fragments loaded directly from
//  global in MFMA fragment order. 256 blocks x 4 independent waves.
//  O2[bhw][32] = sum_k Patch[bhw][k] * Wob[ch][k]
// ---------------------------------------------------------------------------
__global__ __launch_bounds__(256) void k_offs_gemm(const unsigned short* __restrict__ xTb,
                                                   const unsigned short* __restrict__ Wob,
                                                   const unsigned short* __restrict__ zp,
                                                   float* __restrict__ O2) {
  int t = threadIdx.x;
  int wv = t >> 6, lane = t & 63;
  int cl = lane & 15, q = lane >> 4;
  int rowbase = (blockIdx.x * 4 + wv) * 16;
  int row = rowbase + cl;
  int b_ = row >> 12, hw = row & 4095, h = hw >> 6, w = hw & 63;
  const unsigned short* xbb = xTb + (((size_t)b_) << 20);

  const unsigned short* pB0 = Wob + (size_t)cl * KDIM + q * 8;
  const unsigned short* pB1 = Wob + (size_t)(16 + cl) * KDIM + q * 8;

  f32x4 acc[2] = {};

  auto aptr = [&](int kidx) -> const unsigned short* {
    int di = kidx / 3 - 1, dj = kidx % 3 - 1;
    int y = h + di, xx = w + dj;
    bool v = ((unsigned)y < 64u) && ((unsigned)xx < 64u);
    return v ? xbb + (((size_t)((y << 6) + xx)) << 8) + q * 8 : zp + q * 8;
  };

  const unsigned short* pA = aptr(0);
  bf16x8 aC = *(const bf16x8*)pA;
  bf16x8 b0C = *(const bf16x8*)pB0;
  bf16x8 b1C = *(const bf16x8*)pB1;

#pragma unroll 2
  for (int kt = 0; kt < 72; ++kt) {
    bf16x8 aN, b0N, b1N;
    if (kt < 71) {
      int kn = kt + 1;
      if ((kn & 7) == 0) pA = aptr(kn >> 3);
      aN  = *(const bf16x8*)(pA + (kn & 7) * 32);
      b0N = *(const bf16x8*)(pB0 + kn * 32);
      b1N = *(const bf16x8*)(pB1 + kn * 32);
    }
    acc[0] = __builtin_amdgcn_mfma_f32_16x16x32_bf16(aC, b0C, acc[0], 0, 0, 0);
    acc[1] = __builtin_amdgcn_mfma_f32_16x16x32_bf16(aC, b1C, acc[1], 0, 0, 0);
    if (kt < 71) { aC = aN; b0C = b0N; b1C = b1N; }
  }

  // C/D layout: out-row = q*4 + r, out-col = cl
#pragma unroll
  for (int j = 0; j < 2; ++j)
#pragma unroll
    for (int r = 0; r < 4; ++r) {
      int orow = rowbase + q * 4 + r;
      O2[(size_t)orow * 32 + j * 16 + cl] = acc[j][r];
    }
}

// ---------------------------------------------------------------------------
// Kernel 4: sampling weights/offsets table (bias folded here).
//  SW[k][bhw] = {w00,w01,w10,w11 (mask*validity), elem offsets of 4 corners}
// ---------------------------------------------------------------------------
__global__ __launch_bounds__(256) void k_sweights(const float* __restrict__ O2,
                                                  const float* __restrict__ offb,
                                                  float* __restrict__ SW) {
  int gid = blockIdx.x * 256 + threadIdx.x;
  if (gid >= 9 * 16384) return;
  int k = gid >> 14;
  int bhw = gid & 16383;
  int h = (bhw >> 6) & 63, w = bhw & 63;

  const float* o = O2 + (size_t)bhw * 32;
  float dy = o[2 * k]     + offb[2 * k];
  float dx = o[2 * k + 1] + offb[2 * k + 1];
  float mv = o[18 + k]    + offb[18 + k];
  float mask = 1.0f / (1.0f + expf(-mv));

  float py = (float)(h - 1 + k / 3) + dy;
  float px = (float)(w - 1 + k % 3) + dx;
  float y0f = floorf(py), x0f = floorf(px);
  float wy = py - y0f, wx = px - x0f;
  int y0 = (int)y0f, x0 = (int)x0f;
  int y1 = y0 + 1, x1 = x0 + 1;

  float vy0 = (y0 >= 0 && y0 < 64) ? 1.f : 0.f;
  float vy1 = (y1 >= 0 && y1 < 64) ? 1.f : 0.f;
  float vx0 = (x0 >= 0 && x0 < 64) ? 1.f : 0.f;
  float vx1 = (x1 >= 0 && x1 < 64) ? 1.f : 0.f;
  int y0c = min(max(y0, 0), 63), y1c = min(max(y1, 0), 63);
  int x0c = min(max(x0, 0), 63), x1c = min(max(x1, 0), 63);

  float4 wv4;
  wv4.x = (1.f - wy) * (1.f - wx) * vy0 * vx0 * mask;
  wv4.y = (1.f - wy) * wx * vy0 * vx1 * mask;
  wv4.z = wy * (1.f - wx) * vy1 * vx0 * mask;
  wv4.w = wy * wx * vy1 * vx1 * mask;
  uint4 ov;
  ov.x = (unsigned)(((y0c << 6) + x0c) << 8);
  ov.y = (unsigned)(((y0c << 6) + x1c) << 8);
  ov.z = (unsigned)(((y1c << 6) + x0c) << 8);
  ov.w = (unsigned)(((y1c << 6) + x1c) << 8);

  float* p = SW + (size_t)gid * 8;
  *(float4*)p = wv4;
  *(uint4*)(p + 4) = ov;
}

// ---------------------------------------------------------------------------
// Kernel 5: fused sample + main GEMM — NO LDS, NO BARRIERS.
//  Grid 256 blocks x 512 thr = 8 independent waves (2/SIMD).
//  Block: 256m x 64n. Wave: 64m x 32n (acc 4x2).
//  A-fragments direct from Wpk; B-fragments built per-lane: each lane
//  gathers its own row's 4 corners (16 B q-slice) and blends in registers.
//  The 4 m-waves sample identical addresses -> L1 dedups redundant gathers.
// ---------------------------------------------------------------------------
__global__ __launch_bounds__(512) void k_fused(const unsigned short* __restrict__ Wpk,
                                               const unsigned short* __restrict__ xTb,
                                               const float* __restrict__ SW,
                                               float* __restrict__ out) {
  int t = threadIdx.x;
  int wv = t >> 6, lane = t & 63;
  int wm = wv & 3, wn = wv >> 2;
  int cl = lane & 15, q = lane >> 4;
  int nb = blockIdx.x;
  int n0 = nb * 64 + wn * 32;
  int b  = (nb * 64) >> 12;                 // block stays within one batch
  const unsigned short* xb = xTb + ((size_t)b << 20);

  int r0 = n0 + cl;        // j=0 sampled row (bhw)
  int r1 = n0 + 16 + cl;   // j=1 sampled row

  const unsigned short* wpBase = Wpk + ((size_t)(wm * 4 * 64 + lane)) * 8;

  f32x4 acc[4][2] = {};

  float4 wq0, wq1; uint4 ov0, ov1;
  {
    const float* s0 = SW + ((size_t)r0) * 8;
    const float* s1 = SW + ((size_t)r1) * 8;
    wq0 = *(const float4*)s0; ov0 = *(const uint4*)(s0 + 4);
    wq1 = *(const float4*)s1; ov1 = *(const uint4*)(s1 + 4);
  }

  int qo = q * 8;
  u16x8 c00, c01, c02, c03;   // j=0 corners
  u16x8 c10, c11, c12, c13;   // j=1 corners
  bf16x8 aF[4];

  // prologue: loads for kt = 0 (c-offset 0)
  c00 = *(const u16x8*)(xb + ov0.x + qo); c01 = *(const u16x8*)(xb + ov0.y + qo);
  c02 = *(const u16x8*)(xb + ov0.z + qo); c03 = *(const u16x8*)(xb + ov0.w + qo);
  c10 = *(const u16x8*)(xb + ov1.x + qo); c11 = *(const u16x8*)(xb + ov1.y + qo);
  c12 = *(const u16x8*)(xb + ov1.z + qo); c13 = *(const u16x8*)(xb + ov1.w + qo);
#pragma unroll
  for (int i = 0; i < 4; ++i)
    aF[i] = *(const bf16x8*)(wpBase + (size_t)i * 512);

  for (int kt = 0; kt < 72; ++kt) {
    // blend current corners -> bF0, bF1
    bf16x8 bF0, bF1;
    {
      float s[8];
#pragma unroll
      for (int c = 0; c < 8; ++c)
        s[c] = wq0.x * bf2f(c00[c]) + wq0.y * bf2f(c01[c])
             + wq0.z * bf2f(c02[c]) + wq0.w * bf2f(c03[c]);
      union { __hip_bfloat162 h2[4]; bf16x8 v; } pk;
#pragma unroll
      for (int c = 0; c < 4; ++c)
        pk.h2[c] = __float22bfloat162_rn(make_float2(s[2 * c], s[2 * c + 1]));
      bF0 = pk.v;
    }
    {
      float s[8];
#pragma unroll
      for (int c = 0; c < 8; ++c)
        s[c] = wq1.x * bf2f(c10[c]) + wq1.y * bf2f(c11[c])
             + wq1.z * bf2f(c12[c]) + wq1.w * bf2f(c13[c]);
      union { __hip_bfloat162 h2[4]; bf16x8 v; } pk;
#pragma unroll
      for (int c = 0; c < 4; ++c)
        pk.h2[c] = __float22bfloat162_rn(make_float2(s[2 * c], s[2 * c + 1]));
      bF1 = pk.v;
    }

    bf16x8 aN[4];
    if (kt < 71) {
      int kn = kt + 1;
      if ((kn & 7) == 0) {
        int kidx = kn >> 3;
        const float* s0 = SW + ((size_t)((kidx << 14) + r0)) * 8;
        const float* s1 = SW + ((size_t)((kidx << 14) + r1)) * 8;
        wq0 = *(const float4*)s0; ov0 = *(const uint4*)(s0 + 4);
        wq1 = *(const float4*)s1; ov1 = *(const uint4*)(s1 + 4);
      }
      unsigned co = (unsigned)(((kn & 7) << 5) + qo);
      c00 = *(const u16x8*)(xb + ov0.x + co); c01 = *(const u16x8*)(xb + ov0.y + co);
      c02 = *(const u16x8*)(xb + ov0.z + co); c03 = *(const u16x8*)(xb + ov0.w + co);
      c10 = *(const u16x8*)(xb + ov1.x + co); c11 = *(const u16x8*)(xb + ov1.y + co);
      c12 = *(const u16x8*)(xb + ov1.z + co); c13 = *(const u16x8*)(xb + ov1.w + co);
#pragma unroll
      for (int i = 0; i < 4; ++i)
        aN[i] = *(const bf16x8*)(wpBase + ((size_t)kn * 16 + i) * 512);
    }

#pragma unroll
    for (int i = 0; i < 4; ++i) {
      acc[i][0] = __builtin_amdgcn_mfma_f32_16x16x32_bf16(aF[i], bF0, acc[i][0], 0, 0, 0);
      acc[i][1] = __builtin_amdgcn_mfma_f32_16x16x32_bf16(aF[i], bF1, acc[i][1], 0, 0, 0);
    }
    if (kt < 71) {
#pragma unroll
      for (int i = 0; i < 4; ++i) aF[i] = aN[i];
    }
  }

  // epilogue: C/D layout col=lane&15, row=quad*4+reg
  float* ob = out + (((size_t)b) << 20);
  int hwb = (n0 & 4095);
#pragma unroll
  for (int i = 0; i < 4; ++i) {
    int mbase = wm * 64 + i * 16 + q * 4;
#pragma unroll
    for (int j = 0; j < 2; ++j) {
      float* op = ob + hwb + j * 16 + cl;
#pragma unroll
      for (int r = 0; r < 4; ++r)
        op[((size_t)(mbase + r)) << 12] = acc[i][j][r];
    }
  }
}

// ---------------------------------------------------------------------------
extern "C" void kernel_launch(void* const* d_in, const int* in_sizes, int n_in,
                              void* d_out, int out_size, void* d_ws, size_t ws_size,
                              hipStream_t stream) {
  const float* x        = (const float*)d_in[0];
  const float* offset_w = (const float*)d_in[1];
  const float* offset_b = (const float*)d_in[2];
  const float* dcn_w    = (const float*)d_in[3];
  float* out = (float*)d_out;

  char* ws = (char*)d_ws;
  size_t off = 0;
  auto carve = [&](size_t bytes) -> void* {
    void* p = ws + off;
    off += (bytes + 255) & ~(size_t)255;
    return p;
  };
  unsigned short* xTb = (unsigned short*)carve(4ull * 64 * 64 * 256 * 2);   // 8 MB
  unsigned short* Wpk = (unsigned short*)carve(72ull * 8192 * 2);           // 1.125 MB
  unsigned short* Wob = (unsigned short*)carve(32ull * KDIM * 2);           // 144 KB
  unsigned short* zp  = (unsigned short*)carve(512);                        // zero page
  float*          O2  = (float*)carve(16384ull * 32 * 4);                   // 2 MB
  float*          SW  = (float*)carve(9ull * 16384 * 8 * 4);                // 4.5 MB
  (void)ws_size; (void)in_sizes; (void)n_in; (void)out_size;

  k_transpose<<<dim3(128, 8, 4), 256, 0, stream>>>(x, xTb);
  k_wprep<<<dim3((72 * 8192 + 32 * KDIM + 256 + 255) / 256), 256, 0, stream>>>(
      dcn_w, offset_w, Wpk, Wob, zp);
  k_offs_gemm<<<dim3(256), 256, 0, stream>>>(xTb, Wob, zp, O2);
  k_sweights<<<dim3((9 * 16384 + 255) / 256), 256, 0, stream>>>(O2, offset_b, SW);
  k_fused<<<dim3(256), 512, 0, stream>>>(Wpk, xTb, SW, out);
}

// Round 7
// 181.730 us; speedup vs baseline: 1.3644x; 1.3644x over previous
//
#include <hip/hip_runtime.h>
#include <hip/hip_bf16.h>
#include <stdint.h>
#include <math.h>

#define KDIM 2304   // 9 * 256

typedef __attribute__((ext_vector_type(8))) short bf16x8;
typedef __attribute__((ext_vector_type(8))) unsigned short u16x8;
typedef __attribute__((ext_vector_type(4))) float f32x4;

__device__ inline unsigned short f2bf(float f) {
  union { float f; unsigned int u; } v; v.f = f;
  unsigned int u = v.u;
  unsigned int r = (u + 0x7FFFu + ((u >> 16) & 1u)) >> 16;
  return (unsigned short)r;
}
__device__ inline float bf2f(unsigned short h) {
  union { unsigned int u; float f; } v; v.u = ((unsigned int)h) << 16;
  return v.f;
}

// ---------------------------------------------------------------------------
// Kernel 1: x (B,C,H,W) fp32 -> xTb (B,H,W,C) bf16
// ---------------------------------------------------------------------------
__global__ __launch_bounds__(256) void k_transpose(const float* __restrict__ x,
                                                   unsigned short* __restrict__ xTb) {
  __shared__ float tile[32][33];
  int t = threadIdx.x;
  int tx = t & 31, ty = t >> 5;
  int p0 = blockIdx.x * 32;
  int c0 = blockIdx.y * 32;
  int b  = blockIdx.z;
  const float* xb = x + ((size_t)b << 20);
#pragma unroll
  for (int i = 0; i < 4; ++i) {
    int c = c0 + ty + i * 8;
    tile[ty + i * 8][tx] = xb[((size_t)c << 12) + p0 + tx];
  }
  __syncthreads();
  unsigned short* ob = xTb + ((size_t)b << 20);
#pragma unroll
  for (int i = 0; i < 4; ++i) {
    int p = p0 + ty + i * 8;
    ob[(((size_t)p) << 8) + c0 + tx] = f2bf(tile[tx][ty + i * 8]);
  }
}

// ---------------------------------------------------------------------------
// Kernel 2: weight prep (Wpk in A-fragment order; Wob row-major; zero page).
// ---------------------------------------------------------------------------
__global__ __launch_bounds__(256) void k_wprep(const float* __restrict__ dcn_w,
                                               const float* __restrict__ offset_w,
                                               unsigned short* __restrict__ Wpk,
                                               unsigned short* __restrict__ Wob,
                                               unsigned short* __restrict__ zp) {
  int gid = blockIdx.x * 256 + threadIdx.x;
  const int N1 = 72 * 8192;
  const int N2 = 32 * KDIM;
  if (gid < N1) {
    int j = gid & 7;
    int lane = (gid >> 3) & 63;
    int mb = (gid >> 9) & 15;
    int kc = gid >> 13;
    int row = mb * 16 + (lane & 15);
    int gk = kc * 32 + ((lane >> 4) << 3) + j;
    int c = gk & 255, kidx = gk >> 8;
    Wpk[gid] = f2bf(dcn_w[((size_t)(row * 256 + c)) * 9 + kidx]);
  } else if (gid < N1 + N2) {
    int g = gid - N1;
    int ch = g / KDIM, k = g % KDIM;
    int kidx = k >> 8, c = k & 255;
    Wob[g] = (ch < 27) ? f2bf(offset_w[((size_t)(ch * 256 + c)) * 9 + kidx])
                       : (unsigned short)0;
  } else if (gid < N1 + N2 + 256) {
    zp[gid - N1 - N2] = 0;
  }
}

// ---------------------------------------------------------------------------
// Kernel 3: offset conv GEMM, phase-structured (one barrier per kidx).
//  Block: 64 bhw rows x 32 ch, 256 thr / 4 waves, grid 256.
//  Per phase p (kidx): stage patch rows (64x256ch bf16) into LDS (copy,
//  XOR-swizzled 16B slices), then 8 barrier-free MFMA chunks.
// ---------------------------------------------------------------------------
__global__ __launch_bounds__(256) void k_offs_gemm(const unsigned short* __restrict__ xTb,
                                                   const unsigned short* __restrict__ Wob,
                                                   const unsigned short* __restrict__ zp,
                                                   float* __restrict__ O2) {
  __shared__ __align__(16) unsigned short As[2][64 * 256];   // 64 KB total
  int t = threadIdx.x;
  int wv = t >> 6, lane = t & 63;
  int cl = lane & 15, q = lane >> 4;
  int n0 = blockIdx.x * 64;

  // staging role: row sr (0..63), slices (t&3)*8 .. +7 (16B units)
  int sr = t >> 2, sb = (t & 3) * 8;
  int row = n0 + sr;
  int b_ = row >> 12, hw = row & 4095, h = hw >> 6, w = hw & 63;
  const unsigned short* xbb = xTb + ((size_t)b_ << 20);

  f32x4 acc[2] = {};

  auto stage = [&](int p, int bufsel) {
    int di = p / 3 - 1, dj = p % 3 - 1;
    int y = h + di, xx = w + dj;
    bool v = ((unsigned)y < 64u) && ((unsigned)xx < 64u);
    const unsigned short* src = v ? xbb + (((size_t)((y << 6) + xx)) << 8) + sb * 8
                                  : zp;
    unsigned short* dstrow = &As[bufsel][sr * 256];
    int sw_ = sr & 7;
#pragma unroll
    for (int si = 0; si < 8; ++si) {
      int sl = (sb + si) ^ sw_;
      *(u16x8*)(dstrow + sl * 8) = *(const u16x8*)(src + si * 8);
    }
  };

  auto mmphase = [&](int p, int bufsel) {
    const unsigned short* abase = &As[bufsel][0];
#pragma unroll
    for (int kc = 0; kc < 8; ++kc) {
      int kt = p * 8 + kc;
      int sl = (kc * 4 + q) ^ (cl & 7);
      bf16x8 aF = *(const bf16x8*)(abase + (wv * 16 + cl) * 256 + sl * 8);
      bf16x8 bF0 = *(const bf16x8*)(Wob + (size_t)cl * KDIM + kt * 32 + q * 8);
      bf16x8 bF1 = *(const bf16x8*)(Wob + (size_t)(16 + cl) * KDIM + kt * 32 + q * 8);
      acc[0] = __builtin_amdgcn_mfma_f32_16x16x32_bf16(aF, bF0, acc[0], 0, 0, 0);
      acc[1] = __builtin_amdgcn_mfma_f32_16x16x32_bf16(aF, bF1, acc[1], 0, 0, 0);
    }
  };

  stage(0, 0);
  __syncthreads();
#pragma unroll 1
  for (int p = 0; p < 9; ++p) {
    if (p < 8) stage(p + 1, (p + 1) & 1);
    mmphase(p, p & 1);
    __syncthreads();
  }

  // epilogue: out-row = n0 + wv*16 + q*4 + r, col = j*16+cl
#pragma unroll
  for (int j = 0; j < 2; ++j)
#pragma unroll
    for (int r = 0; r < 4; ++r)
      O2[(size_t)(n0 + wv * 16 + q * 4 + r) * 32 + j * 16 + cl] = acc[j][r];
}

// ---------------------------------------------------------------------------
// Kernel 4: sampling weights/offsets table (bias folded here).
// ---------------------------------------------------------------------------
__global__ __launch_bounds__(256) void k_sweights(const float* __restrict__ O2,
                                                  const float* __restrict__ offb,
                                                  float* __restrict__ SW) {
  int gid = blockIdx.x * 256 + threadIdx.x;
  if (gid >= 9 * 16384) return;
  int k = gid >> 14;
  int bhw = gid & 16383;
  int h = (bhw >> 6) & 63, w = bhw & 63;

  const float* o = O2 + (size_t)bhw * 32;
  float dy = o[2 * k]     + offb[2 * k];
  float dx = o[2 * k + 1] + offb[2 * k + 1];
  float mv = o[18 + k]    + offb[18 + k];
  float mask = 1.0f / (1.0f + expf(-mv));

  float py = (float)(h - 1 + k / 3) + dy;
  float px = (float)(w - 1 + k % 3) + dx;
  float y0f = floorf(py), x0f = floorf(px);
  float wy = py - y0f, wx = px - x0f;
  int y0 = (int)y0f, x0 = (int)x0f;
  int y1 = y0 + 1, x1 = x0 + 1;

  float vy0 = (y0 >= 0 && y0 < 64) ? 1.f : 0.f;
  float vy1 = (y1 >= 0 && y1 < 64) ? 1.f : 0.f;
  float vx0 = (x0 >= 0 && x0 < 64) ? 1.f : 0.f;
  float vx1 = (x1 >= 0 && x1 < 64) ? 1.f : 0.f;
  int y0c = min(max(y0, 0), 63), y1c = min(max(y1, 0), 63);
  int x0c = min(max(x0, 0), 63), x1c = min(max(x1, 0), 63);

  float4 wv4;
  wv4.x = (1.f - wy) * (1.f - wx) * vy0 * vx0 * mask;
  wv4.y = (1.f - wy) * wx * vy0 * vx1 * mask;
  wv4.z = wy * (1.f - wx) * vy1 * vx0 * mask;
  wv4.w = wy * wx * vy1 * vx1 * mask;
  uint4 ov;
  ov.x = (unsigned)(((y0c << 6) + x0c) << 8);
  ov.y = (unsigned)(((y0c << 6) + x1c) << 8);
  ov.z = (unsigned)(((y1c << 6) + x0c) << 8);
  ov.w = (unsigned)(((y1c << 6) + x1c) << 8);

  float* p = SW + (size_t)gid * 8;
  *(float4*)p = wv4;
  *(uint4*)(p + 4) = ov;
}

// ---------------------------------------------------------------------------
// Kernel 5: fused sample + main GEMM, phase-structured.
//  Grid 256 x 512 thr (8 waves). Block: 256m x 64n. Wave: 64m x 32n (acc 4x2).
//  Per phase p (kidx): sample full 64-row x 256-ch panel into LDS buf
//  (coalesced gathers + register blend, XOR-swizzled slices), one barrier,
//  then 8 MFMA chunks; sample(p+1) overlaps mfma(p) via double buffer.
//  A-fragments direct from packed Wpk (no LDS).
// ---------------------------------------------------------------------------
__global__ __launch_bounds__(512) void k_fused(const unsigned short* __restrict__ Wpk,
                                               const unsigned short* __restrict__ xTb,
                                               const float* __restrict__ SW,
                                               float* __restrict__ out) {
  __shared__ __align__(16) unsigned short Bs[2][64 * 256];   // 64 KB total
  int t = threadIdx.x;
  int wv = t >> 6, lane = t & 63;
  int wm = wv & 3, wn = wv >> 2;
  int cl = lane & 15, q = lane >> 4;
  int n0 = blockIdx.x * 64;
  int b  = n0 >> 12;
  const unsigned short* xb = xTb + ((size_t)b << 20);

  // sampling role: row sr (0..63), 32 ch: slices s0..s0+3 (16B = 8ch units)
  int sr = t >> 3, s0 = (t & 7) * 4;

  f32x4 acc[4][2] = {};

  auto sample = [&](int p, int bufsel) {
    const float* sw = SW + ((size_t)((p << 14) + n0 + sr)) * 8;
    float4 wq = *(const float4*)sw;
    uint4 ov = *(const uint4*)(sw + 4);
    const unsigned short* p00 = xb + ov.x + s0 * 8;
    const unsigned short* p01 = xb + ov.y + s0 * 8;
    const unsigned short* p10 = xb + ov.z + s0 * 8;
    const unsigned short* p11 = xb + ov.w + s0 * 8;
    unsigned short* dstrow = &Bs[bufsel][sr * 256];
    int sw_ = sr & 7;
#pragma unroll
    for (int si = 0; si < 4; ++si) {
      u16x8 a = *(const u16x8*)(p00 + si * 8);
      u16x8 c = *(const u16x8*)(p01 + si * 8);
      u16x8 d = *(const u16x8*)(p10 + si * 8);
      u16x8 e = *(const u16x8*)(p11 + si * 8);
      float s[8];
#pragma unroll
      for (int c2 = 0; c2 < 8; ++c2)
        s[c2] = wq.x * bf2f(a[c2]) + wq.y * bf2f(c[c2])
              + wq.z * bf2f(d[c2]) + wq.w * bf2f(e[c2]);
      union { __hip_bfloat162 h2[4]; u16x8 v; } pk;
#pragma unroll
      for (int c2 = 0; c2 < 4; ++c2)
        pk.h2[c2] = __float22bfloat162_rn(make_float2(s[2 * c2], s[2 * c2 + 1]));
      int sl = (s0 + si) ^ sw_;
      *(u16x8*)(dstrow + sl * 8) = pk.v;
    }
  };

  auto mmphase = [&](int p, int bufsel) {
    const unsigned short* bbase = &Bs[bufsel][0];
#pragma unroll
    for (int kc = 0; kc < 8; ++kc) {
      int kt = p * 8 + kc;
      bf16x8 aF[4], bF[2];
#pragma unroll
      for (int i = 0; i < 4; ++i)
        aF[i] = *(const bf16x8*)(Wpk + ((size_t)((kt * 16 + wm * 4 + i) * 64 + lane)) * 8);
#pragma unroll
      for (int j = 0; j < 2; ++j) {
        int brow = wn * 32 + j * 16 + cl;
        int sl = (kc * 4 + q) ^ (cl & 7);
        bF[j] = *(const bf16x8*)(bbase + brow * 256 + sl * 8);
      }
#pragma unroll
      for (int i = 0; i < 4; ++i) {
        acc[i][0] = __builtin_amdgcn_mfma_f32_16x16x32_bf16(aF[i], bF[0], acc[i][0], 0, 0, 0);
        acc[i][1] = __builtin_amdgcn_mfma_f32_16x16x32_bf16(aF[i], bF[1], acc[i][1], 0, 0, 0);
      }
    }
  };

  sample(0, 0);
  __syncthreads();
#pragma unroll 1
  for (int p = 0; p < 9; ++p) {
    if (p < 8) sample(p + 1, (p + 1) & 1);
    mmphase(p, p & 1);
    __syncthreads();
  }

  // epilogue: C/D layout col=lane&15, row=quad*4+reg
  float* ob = out + (((size_t)b) << 20);
  int hwb = n0 & 4095;
#pragma unroll
  for (int i = 0; i < 4; ++i) {
    int mbase = wm * 64 + i * 16 + q * 4;
#pragma unroll
    for (int j = 0; j < 2; ++j) {
      float* op = ob + hwb + wn * 32 + j * 16 + cl;
#pragma unroll
      for (int r = 0; r < 4; ++r)
        op[((size_t)(mbase + r)) << 12] = acc[i][j][r];
    }
  }
}

// ---------------------------------------------------------------------------
extern "C" void kernel_launch(void* const* d_in, const int* in_sizes, int n_in,
                              void* d_out, int out_size, void* d_ws, size_t ws_size,
                              hipStream_t stream) {
  const float* x        = (const float*)d_in[0];
  const float* offset_w = (const float*)d_in[1];
  const float* offset_b = (const float*)d_in[2];
  const float* dcn_w    = (const float*)d_in[3];
  float* out = (float*)d_out;

  char* ws = (char*)d_ws;
  size_t off = 0;
  auto carve = [&](size_t bytes) -> void* {
    void* p = ws + off;
    off += (bytes + 255) & ~(size_t)255;
    return p;
  };
  unsigned short* xTb = (unsigned short*)carve(4ull * 64 * 64 * 256 * 2);   // 8 MB
  unsigned short* Wpk = (unsigned short*)carve(72ull * 8192 * 2);           // 1.125 MB
  unsigned short* Wob = (unsigned short*)carve(32ull * KDIM * 2);           // 144 KB
  unsigned short* zp  = (unsigned short*)carve(512);                        // zero page
  float*          O2  = (float*)carve(16384ull * 32 * 4);                   // 2 MB
  float*          SW  = (float*)carve(9ull * 16384 * 8 * 4);                // 4.5 MB
  (void)ws_size; (void)in_sizes; (void)n_in; (void)out_size;

  k_transpose<<<dim3(128, 8, 4), 256, 0, stream>>>(x, xTb);
  k_wprep<<<dim3((72 * 8192 + 32 * KDIM + 256 + 255) / 256), 256, 0, stream>>>(
      dcn_w, offset_w, Wpk, Wob, zp);
  k_offs_gemm<<<dim3(256), 256, 0, stream>>>(xTb, Wob, zp, O2);
  k_sweights<<<dim3((9 * 16384 + 255) / 256), 256, 0, stream>>>(O2, offset_b, SW);
  k_fused<<<dim3(256), 512, 0, stream>>>(Wpk, xTb, SW, out);
}

// Round 8
// 168.032 us; speedup vs baseline: 1.4756x; 1.0815x over previous
//
#include <hip/hip_runtime.h>
#include <hip/hip_bf16.h>
#include <stdint.h>
#include <math.h>

#define KDIM 2304   // 9 * 256

typedef __attribute__((ext_vector_type(8))) short bf16x8;
typedef __attribute__((ext_vector_type(8))) unsigned short u16x8;
typedef __attribute__((ext_vector_type(4))) float f32x4;

__device__ inline unsigned short f2bf(float f) {
  union { float f; unsigned int u; } v; v.f = f;
  unsigned int u = v.u;
  unsigned int r = (u + 0x7FFFu + ((u >> 16) & 1u)) >> 16;
  return (unsigned short)r;
}
__device__ inline float bf2f(unsigned short h) {
  union { unsigned int u; float f; } v; v.u = ((unsigned int)h) << 16;
  return v.f;
}

// ---------------------------------------------------------------------------
// Kernel 1: x (B,C,H,W) fp32 -> xTb (B,H,W,C) bf16
// ---------------------------------------------------------------------------
__global__ __launch_bounds__(256) void k_transpose(const float* __restrict__ x,
                                                   unsigned short* __restrict__ xTb) {
  __shared__ float tile[32][33];
  int t = threadIdx.x;
  int tx = t & 31, ty = t >> 5;
  int p0 = blockIdx.x * 32;
  int c0 = blockIdx.y * 32;
  int b  = blockIdx.z;
  const float* xb = x + ((size_t)b << 20);
#pragma unroll
  for (int i = 0; i < 4; ++i) {
    int c = c0 + ty + i * 8;
    tile[ty + i * 8][tx] = xb[((size_t)c << 12) + p0 + tx];
  }
  __syncthreads();
  unsigned short* ob = xTb + ((size_t)b << 20);
#pragma unroll
  for (int i = 0; i < 4; ++i) {
    int p = p0 + ty + i * 8;
    ob[(((size_t)p) << 8) + c0 + tx] = f2bf(tile[tx][ty + i * 8]);
  }
}

// ---------------------------------------------------------------------------
// Kernel 2: weight prep (Wpk in A-fragment order; Wob row-major; zero page).
// ---------------------------------------------------------------------------
__global__ __launch_bounds__(256) void k_wprep(const float* __restrict__ dcn_w,
                                               const float* __restrict__ offset_w,
                                               unsigned short* __restrict__ Wpk,
                                               unsigned short* __restrict__ Wob,
                                               unsigned short* __restrict__ zp) {
  int gid = blockIdx.x * 256 + threadIdx.x;
  const int N1 = 72 * 8192;
  const int N2 = 32 * KDIM;
  if (gid < N1) {
    int j = gid & 7;
    int lane = (gid >> 3) & 63;
    int mb = (gid >> 9) & 15;
    int kc = gid >> 13;
    int row = mb * 16 + (lane & 15);
    int gk = kc * 32 + ((lane >> 4) << 3) + j;
    int c = gk & 255, kidx = gk >> 8;
    Wpk[gid] = f2bf(dcn_w[((size_t)(row * 256 + c)) * 9 + kidx]);
  } else if (gid < N1 + N2) {
    int g = gid - N1;
    int ch = g / KDIM, k = g % KDIM;
    int kidx = k >> 8, c = k & 255;
    Wob[g] = (ch < 27) ? f2bf(offset_w[((size_t)(ch * 256 + c)) * 9 + kidx])
                       : (unsigned short)0;
  } else if (gid < N1 + N2 + 256) {
    zp[gid - N1 - N2] = 0;
  }
}

// ---------------------------------------------------------------------------
// Kernel 3: offset conv GEMM, R5-fused-style: dbuf LDS patch staging,
//  one barrier per kt, prefetch-1. BM=32 rows, grid 512 (2 blocks/CU),
//  256 thr / 4 waves: wave = 16m x 16n (acc 1), wm=wv&1, wn=wv>>1.
//  bF direct from L2-resident Wob.
// ---------------------------------------------------------------------------
__global__ __launch_bounds__(256) void k_offs_gemm(const unsigned short* __restrict__ xTb,
                                                   const unsigned short* __restrict__ Wob,
                                                   const unsigned short* __restrict__ zp,
                                                   float* __restrict__ O2) {
  __shared__ __align__(16) unsigned short As[2][32 * 40];   // 5 KB
  int t = threadIdx.x;
  int wv = t >> 6, lane = t & 63;
  int cl = lane & 15, q = lane >> 4;
  int wm = wv & 1, wn = wv >> 1;
  int n0 = blockIdx.x * 32;

  // staging role: row sr (0..31), 4-ch unit u (0..7)
  int sr = t >> 3, u = t & 7;
  int row = n0 + sr;
  int b_ = row >> 12, hw = row & 4095, h = hw >> 6, w = hw & 63;
  const unsigned short* xbb = xTb + ((size_t)b_ << 20);

  auto aptr = [&](int kidx) -> const unsigned short* {
    int di = kidx / 3 - 1, dj = kidx % 3 - 1;
    int y = h + di, xx = w + dj;
    bool v = ((unsigned)y < 64u) && ((unsigned)xx < 64u);
    return v ? xbb + (((size_t)((y << 6) + xx)) << 8) : zp;
  };

  f32x4 acc = {};
  const unsigned short* pA = aptr(0);
  ushort4 qc = *(const ushort4*)(pA + u * 4);

  for (int kt = 0; kt < 72; ++kt) {
    *(ushort4*)(&As[kt & 1][sr * 40 + u * 4]) = qc;
    if (kt < 71) {
      int kn = kt + 1;
      if ((kn & 7) == 0) pA = aptr(kn >> 3);
      qc = *(const ushort4*)(pA + (kn & 7) * 32 + u * 4);
    }
    __syncthreads();
    bf16x8 aF = *(const bf16x8*)(&As[kt & 1][(wm * 16 + cl) * 40 + q * 8]);
    bf16x8 bF = *(const bf16x8*)(Wob + (size_t)(wn * 16 + cl) * KDIM + kt * 32 + q * 8);
    acc = __builtin_amdgcn_mfma_f32_16x16x32_bf16(aF, bF, acc, 0, 0, 0);
  }

  // epilogue: C/D layout col=cl (ch), row=q*4+r (bhw within tile)
#pragma unroll
  for (int r = 0; r < 4; ++r)
    O2[(size_t)(n0 + wm * 16 + q * 4 + r) * 32 + wn * 16 + cl] = acc[r];
}

// ---------------------------------------------------------------------------
// Kernel 4: sampling weights/offsets table (bias folded here).
// ---------------------------------------------------------------------------
__global__ __launch_bounds__(256) void k_sweights(const float* __restrict__ O2,
                                                  const float* __restrict__ offb,
                                                  float* __restrict__ SW) {
  int gid = blockIdx.x * 256 + threadIdx.x;
  if (gid >= 9 * 16384) return;
  int k = gid >> 14;
  int bhw = gid & 16383;
  int h = (bhw >> 6) & 63, w = bhw & 63;

  const float* o = O2 + (size_t)bhw * 32;
  float dy = o[2 * k]     + offb[2 * k];
  float dx = o[2 * k + 1] + offb[2 * k + 1];
  float mv = o[18 + k]    + offb[18 + k];
  float mask = 1.0f / (1.0f + expf(-mv));

  float py = (float)(h - 1 + k / 3) + dy;
  float px = (float)(w - 1 + k % 3) + dx;
  float y0f = floorf(py), x0f = floorf(px);
  float wy = py - y0f, wx = px - x0f;
  int y0 = (int)y0f, x0 = (int)x0f;
  int y1 = y0 + 1, x1 = x0 + 1;

  float vy0 = (y0 >= 0 && y0 < 64) ? 1.f : 0.f;
  float vy1 = (y1 >= 0 && y1 < 64) ? 1.f : 0.f;
  float vx0 = (x0 >= 0 && x0 < 64) ? 1.f : 0.f;
  float vx1 = (x1 >= 0 && x1 < 64) ? 1.f : 0.f;
  int y0c = min(max(y0, 0), 63), y1c = min(max(y1, 0), 63);
  int x0c = min(max(x0, 0), 63), x1c = min(max(x1, 0), 63);

  float4 wv4;
  wv4.x = (1.f - wy) * (1.f - wx) * vy0 * vx0 * mask;
  wv4.y = (1.f - wy) * wx * vy0 * vx1 * mask;
  wv4.z = wy * (1.f - wx) * vy1 * vx0 * mask;
  wv4.w = wy * wx * vy1 * vx1 * mask;
  uint4 ov;
  ov.x = (unsigned)(((y0c << 6) + x0c) << 8);
  ov.y = (unsigned)(((y0c << 6) + x1c) << 8);
  ov.z = (unsigned)(((y1c << 6) + x0c) << 8);
  ov.w = (unsigned)(((y1c << 6) + x1c) << 8);

  float* p = SW + (size_t)gid * 8;
  *(float4*)p = wv4;
  *(uint4*)(p + 4) = ov;
}

// ---------------------------------------------------------------------------
// Kernel 5: fused sample + main GEMM — R5 structure, m-split for occupancy.
//  Grid (256 n-tiles, 2 m-halves) = 512 blocks (2/CU), 256 thr / 4 waves.
//  Block: 128m x 64n, BK=32. Wave: 64m x 32n (acc 4x2), wm=wv&1, wn=wv>>1.
//  A-fragments direct from packed Wpk (prefetch-1); sampled B tile through
//  double-buffered padded LDS (40-short rows); one barrier per kt.
// ---------------------------------------------------------------------------
__global__ __launch_bounds__(256) void k_fused(const unsigned short* __restrict__ Wpk,
                                               const unsigned short* __restrict__ xTb,
                                               const float* __restrict__ SW,
                                               float* __restrict__ out) {
  __shared__ __align__(16) unsigned short Bs[2][64 * 40];  // 10 KB
  int t = threadIdx.x;
  int wv = t >> 6, lane = t & 63;
  int wm = wv & 1, wn = wv >> 1;
  int cl = lane & 15, q = lane >> 4;
  int n0 = blockIdx.x * 64;
  int mh = blockIdx.y;               // m-half: rows mh*128 .. mh*128+127
  int b  = n0 >> 12;
  const unsigned short* xb = xTb + ((size_t)b << 20);

  // sampling role: row r (0..63), channel octet g (0..3) -> ch = g*8
  int r = t >> 2, g = t & 3;
  int ch0 = g * 8;
  int bsw = r * 40 + ch0;

  f32x4 acc[4][2] = {};

  float4 wq; uint4 ov;
  {
    const float* sw = SW + ((size_t)(n0 + r)) * 8;
    wq = *(const float4*)sw;
    ov = *(const uint4*)(sw + 4);
  }
  u16x8 q00, q01, q10, q11;
  bf16x8 aF[4], aFn[4];

  // prologue: gathers + A for kt = 0
  q00 = *(const u16x8*)(xb + ov.x + ch0);
  q01 = *(const u16x8*)(xb + ov.y + ch0);
  q10 = *(const u16x8*)(xb + ov.z + ch0);
  q11 = *(const u16x8*)(xb + ov.w + ch0);
#pragma unroll
  for (int i = 0; i < 4; ++i)
    aF[i] = *(const bf16x8*)(Wpk + ((size_t)((mh * 8 + wm * 4 + i) * 64 + lane)) * 8);

  for (int kt = 0; kt < 72; ++kt) {
    // blend current gathers -> Bs[kt&1]
    {
      float s[8];
#pragma unroll
      for (int c = 0; c < 8; ++c)
        s[c] = wq.x * bf2f(q00[c]) + wq.y * bf2f(q01[c])
             + wq.z * bf2f(q10[c]) + wq.w * bf2f(q11[c]);
      union { __hip_bfloat162 h2[4]; u16x8 v; } pk;
#pragma unroll
      for (int c = 0; c < 4; ++c)
        pk.h2[c] = __float22bfloat162_rn(make_float2(s[2 * c], s[2 * c + 1]));
      *(u16x8*)(&Bs[kt & 1][bsw]) = pk.v;
    }

    // prefetch kt+1 (covered by barrier + MFMA below)
    if (kt < 71) {
      int kn = kt + 1;
      if ((kn & 7) == 0) {
        const float* sw = SW + ((size_t)(((kn >> 3) << 14) + n0 + r)) * 8;
        wq = *(const float4*)sw;
        ov = *(const uint4*)(sw + 4);
      }
      unsigned co = (unsigned)(((kn & 7) << 5) + ch0);
      q00 = *(const u16x8*)(xb + ov.x + co);
      q01 = *(const u16x8*)(xb + ov.y + co);
      q10 = *(const u16x8*)(xb + ov.z + co);
      q11 = *(const u16x8*)(xb + ov.w + co);
#pragma unroll
      for (int i = 0; i < 4; ++i)
        aFn[i] = *(const bf16x8*)(Wpk + ((size_t)((kn * 16 + mh * 8 + wm * 4 + i) * 64 + lane)) * 8);
    }

    __syncthreads();
    bf16x8 bF[2];
#pragma unroll
    for (int j = 0; j < 2; ++j)
      bF[j] = *(const bf16x8*)(&Bs[kt & 1][(wn * 32 + j * 16 + cl) * 40 + q * 8]);
#pragma unroll
    for (int i = 0; i < 4; ++i) {
      acc[i][0] = __builtin_amdgcn_mfma_f32_16x16x32_bf16(aF[i], bF[0], acc[i][0], 0, 0, 0);
      acc[i][1] = __builtin_amdgcn_mfma_f32_16x16x32_bf16(aF[i], bF[1], acc[i][1], 0, 0, 0);
    }
    if (kt < 71) {
#pragma unroll
      for (int i = 0; i < 4; ++i) aF[i] = aFn[i];
    }
  }

  // epilogue: C/D layout col=lane&15, row=quad*4+reg
  float* ob = out + (((size_t)b) << 20);
  int hwb = n0 & 4095;
#pragma unroll
  for (int i = 0; i < 4; ++i) {
    int mbase = mh * 128 + wm * 64 + i * 16 + q * 4;
#pragma unroll
    for (int j = 0; j < 2; ++j) {
      float* op = ob + hwb + wn * 32 + j * 16 + cl;
#pragma unroll
      for (int rr = 0; rr < 4; ++rr)
        op[((size_t)(mbase + rr)) << 12] = acc[i][j][rr];
    }
  }
}

// ---------------------------------------------------------------------------
extern "C" void kernel_launch(void* const* d_in, const int* in_sizes, int n_in,
                              void* d_out, int out_size, void* d_ws, size_t ws_size,
                              hipStream_t stream) {
  const float* x        = (const float*)d_in[0];
  const float* offset_w = (const float*)d_in[1];
  const float* offset_b = (const float*)d_in[2];
  const float* dcn_w    = (const float*)d_in[3];
  float* out = (float*)d_out;

  char* ws = (char*)d_ws;
  size_t off = 0;
  auto carve = [&](size_t bytes) -> void* {
    void* p = ws + off;
    off += (bytes + 255) & ~(size_t)255;
    return p;
  };
  unsigned short* xTb = (unsigned short*)carve(4ull * 64 * 64 * 256 * 2);   // 8 MB
  unsigned short* Wpk = (unsigned short*)carve(72ull * 8192 * 2);           // 1.125 MB
  unsigned short* Wob = (unsigned short*)carve(32ull * KDIM * 2);           // 144 KB
  unsigned short* zp  = (unsigned short*)carve(512);                        // zero page
  float*          O2  = (float*)carve(16384ull * 32 * 4);                   // 2 MB
  float*          SW  = (float*)carve(9ull * 16384 * 8 * 4);                // 4.5 MB
  (void)ws_size; (void)in_sizes; (void)n_in; (void)out_size;

  k_transpose<<<dim3(128, 8, 4), 256, 0, stream>>>(x, xTb);
  k_wprep<<<dim3((72 * 8192 + 32 * KDIM + 256 + 255) / 256), 256, 0, stream>>>(
      dcn_w, offset_w, Wpk, Wob, zp);
  k_offs_gemm<<<dim3(512), 256, 0, stream>>>(xTb, Wob, zp, O2);
  k_sweights<<<dim3((9 * 16384 + 255) / 256), 256, 0, stream>>>(O2, offset_b, SW);
  k_fused<<<dim3(256, 2), 256, 0, stream>>>(Wpk, xTb, SW, out);
}

// Round 9
// 164.218 us; speedup vs baseline: 1.5099x; 1.0232x over previous
//
#include <hip/hip_runtime.h>
#include <hip/hip_bf16.h>
#include <stdint.h>
#include <math.h>

#define KDIM 2304   // 9 * 256
#define PS   1296   // kc-plane stride in shorts: 32*40 + 16 (plane shift = 8 banks)
#define PB   10368  // phase buffer: 8 * PS

typedef __attribute__((ext_vector_type(8))) short bf16x8;
typedef __attribute__((ext_vector_type(8))) unsigned short u16x8;
typedef __attribute__((ext_vector_type(4))) float f32x4;

__device__ inline unsigned short f2bf(float f) {
  union { float f; unsigned int u; } v; v.f = f;
  unsigned int u = v.u;
  unsigned int r = (u + 0x7FFFu + ((u >> 16) & 1u)) >> 16;
  return (unsigned short)r;
}
__device__ inline float bf2f(unsigned short h) {
  union { unsigned int u; float f; } v; v.u = ((unsigned int)h) << 16;
  return v.f;
}

// ---------------------------------------------------------------------------
// Kernel 1: x (B,C,H,W) fp32 -> xTb (B,H,W,C) bf16
// ---------------------------------------------------------------------------
__global__ __launch_bounds__(256) void k_transpose(const float* __restrict__ x,
                                                   unsigned short* __restrict__ xTb) {
  __shared__ float tile[32][33];
  int t = threadIdx.x;
  int tx = t & 31, ty = t >> 5;
  int p0 = blockIdx.x * 32;
  int c0 = blockIdx.y * 32;
  int b  = blockIdx.z;
  const float* xb = x + ((size_t)b << 20);
#pragma unroll
  for (int i = 0; i < 4; ++i) {
    int c = c0 + ty + i * 8;
    tile[ty + i * 8][tx] = xb[((size_t)c << 12) + p0 + tx];
  }
  __syncthreads();
  unsigned short* ob = xTb + ((size_t)b << 20);
#pragma unroll
  for (int i = 0; i < 4; ++i) {
    int p = p0 + ty + i * 8;
    ob[(((size_t)p) << 8) + c0 + tx] = f2bf(tile[tx][ty + i * 8]);
  }
}

// ---------------------------------------------------------------------------
// Kernel 2: weight prep (Wpk in A-fragment order; Wob row-major; zero page).
// ---------------------------------------------------------------------------
__global__ __launch_bounds__(256) void k_wprep(const float* __restrict__ dcn_w,
                                               const float* __restrict__ offset_w,
                                               unsigned short* __restrict__ Wpk,
                                               unsigned short* __restrict__ Wob,
                                               unsigned short* __restrict__ zp) {
  int gid = blockIdx.x * 256 + threadIdx.x;
  const int N1 = 72 * 8192;
  const int N2 = 32 * KDIM;
  if (gid < N1) {
    int j = gid & 7;
    int lane = (gid >> 3) & 63;
    int mb = (gid >> 9) & 15;
    int kc = gid >> 13;
    int row = mb * 16 + (lane & 15);
    int gk = kc * 32 + ((lane >> 4) << 3) + j;
    int c = gk & 255, kidx = gk >> 8;
    Wpk[gid] = f2bf(dcn_w[((size_t)(row * 256 + c)) * 9 + kidx]);
  } else if (gid < N1 + N2) {
    int g = gid - N1;
    int ch = g / KDIM, k = g % KDIM;
    int kidx = k >> 8, c = k & 255;
    Wob[g] = (ch < 27) ? f2bf(offset_w[((size_t)(ch * 256 + c)) * 9 + kidx])
                       : (unsigned short)0;
  } else if (gid < N1 + N2 + 256) {
    zp[gid - N1 - N2] = 0;
  }
}

// ---------------------------------------------------------------------------
// Kernel 3: offset conv GEMM, phase-structured (1 barrier per kidx phase).
//  BM=32 rows x 32 ch, grid 512 (2 blocks/CU), 256 thr / 4 waves.
//  Wave = 16m x 16n (acc 1): wm=wv&1, wn=wv>>1.
//  Per phase: stage 32x256 patch panel (copy) into dbuf kc-plane LDS,
//  then 8 barrier-free MFMA chunks; bF direct from L2-resident Wob.
// ---------------------------------------------------------------------------
__global__ __launch_bounds__(256, 2) void k_offs_gemm(const unsigned short* __restrict__ xTb,
                                                      const unsigned short* __restrict__ Wob,
                                                      const unsigned short* __restrict__ zp,
                                                      float* __restrict__ O2) {
  __shared__ __align__(16) unsigned short As[2 * PB];   // 41.5 KB
  int t = threadIdx.x;
  int wv = t >> 6, lane = t & 63;
  int cl = lane & 15, q = lane >> 4;
  int wm = wv & 1, wn = wv >> 1;
  int n0 = blockIdx.x * 32;

  // staging role: row r (0..31), kc chunk (0..7) -> channels [kc*32, kc*32+32)
  int r = t >> 3, kc = t & 7;
  int row = n0 + r;
  int b_ = row >> 12, hw = row & 4095, h = hw >> 6, w = hw & 63;
  const unsigned short* xbb = xTb + ((size_t)b_ << 20);

  f32x4 acc = {};

  auto stage = [&](int p, int bufsel) {
    int di = p / 3 - 1, dj = p % 3 - 1;
    int y = h + di, xx = w + dj;
    bool v = ((unsigned)y < 64u) && ((unsigned)xx < 64u);
    const unsigned short* src = v ? xbb + (((size_t)((y << 6) + xx)) << 8) + kc * 32
                                  : zp;
    unsigned short* dst = As + bufsel * PB + kc * PS + r * 40;
#pragma unroll
    for (int si = 0; si < 4; ++si)
      *(u16x8*)(dst + si * 8) = *(const u16x8*)(src + si * 8);
  };

  auto mmphase = [&](int p, int bufsel) {
    const unsigned short* base = As + bufsel * PB;
#pragma unroll
    for (int k2 = 0; k2 < 8; ++k2) {
      int kt = p * 8 + k2;
      bf16x8 aF = *(const bf16x8*)(base + k2 * PS + (wm * 16 + cl) * 40 + q * 8);
      bf16x8 bF = *(const bf16x8*)(Wob + (size_t)(wn * 16 + cl) * KDIM + kt * 32 + q * 8);
      acc = __builtin_amdgcn_mfma_f32_16x16x32_bf16(aF, bF, acc, 0, 0, 0);
    }
  };

  stage(0, 0);
  __syncthreads();
#pragma unroll 1
  for (int p = 0; p < 9; ++p) {
    if (p < 8) stage(p + 1, (p + 1) & 1);
    mmphase(p, p & 1);
    __syncthreads();
  }

  // epilogue: out-row = n0 + wm*16 + q*4 + r, col = wn*16 + cl
#pragma unroll
  for (int rr = 0; rr < 4; ++rr)
    O2[(size_t)(n0 + wm * 16 + q * 4 + rr) * 32 + wn * 16 + cl] = acc[rr];
}

// ---------------------------------------------------------------------------
// Kernel 4: sampling weights/offsets table (bias folded here).
// ---------------------------------------------------------------------------
__global__ __launch_bounds__(256) void k_sweights(const float* __restrict__ O2,
                                                  const float* __restrict__ offb,
                                                  float* __restrict__ SW) {
  int gid = blockIdx.x * 256 + threadIdx.x;
  if (gid >= 9 * 16384) return;
  int k = gid >> 14;
  int bhw = gid & 16383;
  int h = (bhw >> 6) & 63, w = bhw & 63;

  const float* o = O2 + (size_t)bhw * 32;
  float dy = o[2 * k]     + offb[2 * k];
  float dx = o[2 * k + 1] + offb[2 * k + 1];
  float mv = o[18 + k]    + offb[18 + k];
  float mask = 1.0f / (1.0f + expf(-mv));

  float py = (float)(h - 1 + k / 3) + dy;
  float px = (float)(w - 1 + k % 3) + dx;
  float y0f = floorf(py), x0f = floorf(px);
  float wy = py - y0f, wx = px - x0f;
  int y0 = (int)y0f, x0 = (int)x0f;
  int y1 = y0 + 1, x1 = x0 + 1;

  float vy0 = (y0 >= 0 && y0 < 64) ? 1.f : 0.f;
  float vy1 = (y1 >= 0 && y1 < 64) ? 1.f : 0.f;
  float vx0 = (x0 >= 0 && x0 < 64) ? 1.f : 0.f;
  float vx1 = (x1 >= 0 && x1 < 64) ? 1.f : 0.f;
  int y0c = min(max(y0, 0), 63), y1c = min(max(y1, 0), 63);
  int x0c = min(max(x0, 0), 63), x1c = min(max(x1, 0), 63);

  float4 wv4;
  wv4.x = (1.f - wy) * (1.f - wx) * vy0 * vx0 * mask;
  wv4.y = (1.f - wy) * wx * vy0 * vx1 * mask;
  wv4.z = wy * (1.f - wx) * vy1 * vx0 * mask;
  wv4.w = wy * wx * vy1 * vx1 * mask;
  uint4 ov;
  ov.x = (unsigned)(((y0c << 6) + x0c) << 8);
  ov.y = (unsigned)(((y0c << 6) + x1c) << 8);
  ov.z = (unsigned)(((y1c << 6) + x0c) << 8);
  ov.w = (unsigned)(((y1c << 6) + x1c) << 8);

  float* p = SW + (size_t)gid * 8;
  *(float4*)p = wv4;
  *(uint4*)(p + 4) = ov;
}

// ---------------------------------------------------------------------------
// Kernel 5: fused sample + main GEMM, phase-structured.
//  BM=256 (full M) x BN=32, grid 512 (2 blocks/CU), 256 thr / 4 waves.
//  Wave: 64m x 32n (acc 4x2). One barrier per kidx phase (9 total).
//  Per phase: sample 32-row x 256-ch panel into dbuf kc-plane LDS
//  (coalesced gathers + register blend); mfma(p) overlaps sample(p+1)
//  of the co-resident block. A-fragments direct from packed Wpk with
//  per-kc register prefetch (inner loop is barrier-free).
// ---------------------------------------------------------------------------
__global__ __launch_bounds__(256, 2) void k_fused(const unsigned short* __restrict__ Wpk,
                                                  const unsigned short* __restrict__ xTb,
                                                  const float* __restrict__ SW,
                                                  float* __restrict__ out) {
  __shared__ __align__(16) unsigned short Bs[2 * PB];   // 41.5 KB
  int t = threadIdx.x;
  int wv = t >> 6, lane = t & 63;
  int cl = lane & 15, q = lane >> 4;
  int n0 = blockIdx.x * 32;
  int b  = n0 >> 12;
  const unsigned short* xb = xTb + ((size_t)b << 20);

  // sampling role: row r (0..31), kc chunk (0..7) -> channels [kc*32, +32)
  int r = t >> 3, kc = t & 7;

  f32x4 acc[4][2] = {};

  auto sample = [&](int p, int bufsel) {
    const float* sw = SW + ((size_t)((p << 14) + n0 + r)) * 8;
    float4 wq = *(const float4*)sw;
    uint4 ov = *(const uint4*)(sw + 4);
    int co = kc * 32;
    const unsigned short* p00 = xb + ov.x + co;
    const unsigned short* p01 = xb + ov.y + co;
    const unsigned short* p10 = xb + ov.z + co;
    const unsigned short* p11 = xb + ov.w + co;
    u16x8 ca[4], cb[4], cc[4], cd[4];
#pragma unroll
    for (int si = 0; si < 4; ++si) {
      ca[si] = *(const u16x8*)(p00 + si * 8);
      cb[si] = *(const u16x8*)(p01 + si * 8);
      cc[si] = *(const u16x8*)(p10 + si * 8);
      cd[si] = *(const u16x8*)(p11 + si * 8);
    }
    unsigned short* dst = Bs + bufsel * PB + kc * PS + r * 40;
#pragma unroll
    for (int si = 0; si < 4; ++si) {
      float s[8];
#pragma unroll
      for (int c2 = 0; c2 < 8; ++c2)
        s[c2] = wq.x * bf2f(ca[si][c2]) + wq.y * bf2f(cb[si][c2])
              + wq.z * bf2f(cc[si][c2]) + wq.w * bf2f(cd[si][c2]);
      union { __hip_bfloat162 h2[4]; u16x8 v; } pk;
#pragma unroll
      for (int c2 = 0; c2 < 4; ++c2)
        pk.h2[c2] = __float22bfloat162_rn(make_float2(s[2 * c2], s[2 * c2 + 1]));
      *(u16x8*)(dst + si * 8) = pk.v;
    }
  };

  auto mmphase = [&](int p, int bufsel) {
    const unsigned short* base = Bs + bufsel * PB;
    bf16x8 aF[4], aFn[4];
#pragma unroll
    for (int i = 0; i < 4; ++i)
      aF[i] = *(const bf16x8*)(Wpk + ((size_t)((p * 8 * 16 + wv * 4 + i) * 64 + lane)) * 8);
#pragma unroll
    for (int k2 = 0; k2 < 8; ++k2) {
      if (k2 < 7) {
        int kt = p * 8 + k2 + 1;
#pragma unroll
        for (int i = 0; i < 4; ++i)
          aFn[i] = *(const bf16x8*)(Wpk + ((size_t)((kt * 16 + wv * 4 + i) * 64 + lane)) * 8);
      }
      bf16x8 bF[2];
#pragma unroll
      for (int j = 0; j < 2; ++j)
        bF[j] = *(const bf16x8*)(base + k2 * PS + (j * 16 + cl) * 40 + q * 8);
#pragma unroll
      for (int i = 0; i < 4; ++i) {
        acc[i][0] = __builtin_amdgcn_mfma_f32_16x16x32_bf16(aF[i], bF[0], acc[i][0], 0, 0, 0);
        acc[i][1] = __builtin_amdgcn_mfma_f32_16x16x32_bf16(aF[i], bF[1], acc[i][1], 0, 0, 0);
      }
      if (k2 < 7) {
#pragma unroll
        for (int i = 0; i < 4; ++i) aF[i] = aFn[i];
      }
    }
  };

  sample(0, 0);
  __syncthreads();
#pragma unroll 1
  for (int p = 0; p < 9; ++p) {
    if (p < 8) sample(p + 1, (p + 1) & 1);
    mmphase(p, p & 1);
    __syncthreads();
  }

  // epilogue: C/D layout col=lane&15, row=quad*4+reg
  float* ob = out + (((size_t)b) << 20);
  int hwb = n0 & 4095;
#pragma unroll
  for (int i = 0; i < 4; ++i) {
    int mbase = wv * 64 + i * 16 + q * 4;
#pragma unroll
    for (int j = 0; j < 2; ++j) {
      float* op = ob + hwb + j * 16 + cl;
#pragma unroll
      for (int rr = 0; rr < 4; ++rr)
        op[((size_t)(mbase + rr)) << 12] = acc[i][j][rr];
    }
  }
}

// ---------------------------------------------------------------------------
extern "C" void kernel_launch(void* const* d_in, const int* in_sizes, int n_in,
                              void* d_out, int out_size, void* d_ws, size_t ws_size,
                              hipStream_t stream) {
  const float* x        = (const float*)d_in[0];
  const float* offset_w = (const float*)d_in[1];
  const float* offset_b = (const float*)d_in[2];
  const float* dcn_w    = (const float*)d_in[3];
  float* out = (float*)d_out;

  char* ws = (char*)d_ws;
  size_t off = 0;
  auto carve = [&](size_t bytes) -> void* {
    void* p = ws + off;
    off += (bytes + 255) & ~(size_t)255;
    return p;
  };
  unsigned short* xTb = (unsigned short*)carve(4ull * 64 * 64 * 256 * 2);   // 8 MB
  unsigned short* Wpk = (unsigned short*)carve(72ull * 8192 * 2);           // 1.125 MB
  unsigned short* Wob = (unsigned short*)carve(32ull * KDIM * 2);           // 144 KB
  unsigned short* zp  = (unsigned short*)carve(512);                        // zero page
  float*          O2  = (float*)carve(16384ull * 32 * 4);                   // 2 MB
  float*          SW  = (float*)carve(9ull * 16384 * 8 * 4);                // 4.5 MB
  (void)ws_size; (void)in_sizes; (void)n_in; (void)out_size;

  k_transpose<<<dim3(128, 8, 4), 256, 0, stream>>>(x, xTb);
  k_wprep<<<dim3((72 * 8192 + 32 * KDIM + 256 + 255) / 256), 256, 0, stream>>>(
      dcn_w, offset_w, Wpk, Wob, zp);
  k_offs_gemm<<<dim3(512), 256, 0, stream>>>(xTb, Wob, zp, O2);
  k_sweights<<<dim3((9 * 16384 + 255) / 256), 256, 0, stream>>>(O2, offset_b, SW);
  k_fused<<<dim3(512), 256, 0, stream>>>(Wpk, xTb, SW, out);
}